// Round 5
// baseline (238.921 us; speedup 1.0000x reference)
//
#include <hip/hip_runtime.h>
#include <hip/hip_bf16.h>
#include <stdint.h>

// ---------------------------------------------------------------------------
// PoseFeatureExtractor fused kernel for MI355X (gfx950) — round 5
//   - vel/acc FOLDED INTO W1 (exact, via index-clamp at sequence start):
//     hidden_s = p_s·(Wp+Wv+Wa) + p_{s-1}·(-Wv-2Wa) + p_{s-2}·Wa + ang_s·Wang
//     K layout: [96|96|96|64] = 352 (3 position groups + angles), jw folded in
//   - phase 0 = centered-scaled P-tile fill (66x75, one pass) + angles only
//   - LDS 34.3KB single aliased region -> 4 blocks/CU = 32 waves/CU (100%)
//   - conflict-aware strides: Ptile 100, ang 72, hid 268 (2-way = free)
// ---------------------------------------------------------------------------

#define S_    2048
#define MT_   64
#define TPB   512
#define HID_  256
#define OUT_  128
#define NK1   11            // K-chunks layer 1 (352/32)

typedef __attribute__((ext_vector_type(8))) short   short8;   // bf16x8 MFMA frag
typedef __attribute__((ext_vector_type(4))) float   floatx4;  // fp32x4 MFMA acc

// edge tables packed as nibbles: c0[e] = (C0M>>4e)&15 ; c1[e] = ((C1M>>4e)&15)+1
#define C0M 0x0ECDB118675110ULL
#define C1M 0x0FDECBA9786540ULL

__device__ __forceinline__ unsigned short bf16_bits(float v) {
    union { float f; unsigned u; } x; x.f = v;
    unsigned r = x.u + 0x7fffu + ((x.u >> 16) & 1u);   // RNE
    return (unsigned short)(r >> 16);
}

__device__ __forceinline__ unsigned pkbf16(float a, float b) {
#if __has_builtin(__builtin_amdgcn_cvt_pk_bf16_f32)
    auto v = __builtin_amdgcn_cvt_pk_bf16_f32(a, b);   // RNE, 1 instr
    unsigned u; __builtin_memcpy(&u, &v, 4); return u;
#else
    return (unsigned)bf16_bits(a) | ((unsigned)bf16_bits(b) << 16);
#endif
}

// |err| <= 6.7e-5 abs (A&S 4.4.45) — far below bf16 feature quantization
__device__ __forceinline__ float facos(float x) {
    float ax = fabsf(x);
    float p = fmaf(ax, -0.0187293f, 0.0742610f);
    p = fmaf(ax, p, -0.2121144f);
    p = fmaf(ax, p, 1.5707288f);
    float r = __builtin_amdgcn_sqrtf(1.f - ax) * p;
    return x < 0.f ? 3.14159265358979f - r : r;
}

// --------------------------- prep kernel -----------------------------------
// Build folded W1' (352 x 256) with vel/acc/jw/BN folded in, pack to MFMA
// B-frag order (blk = contiguous 1KB; lane l holds B[k=(l>>4)*8+j][n=l&15]).
//   k in [0,96):   p_s     rows: (Wp+Wv+Wa)·jw·a      (k<75, else 0)
//   k in [96,192): p_{s-1} rows: -(Wv+2Wa)·jw·a
//   k in [192,288):p_{s-2} rows: Wa·jw·a
//   k in [288,352):angles  rows: Wang·jw·a            (k-288<39, else 0)
__global__ void prep_kernel(const float* __restrict__ W1, const float* __restrict__ b1,
                            const float* __restrict__ gamma, const float* __restrict__ beta,
                            const float* __restrict__ rmean, const float* __restrict__ rvar,
                            const float* __restrict__ W2, const float* __restrict__ jw,
                            unsigned short* __restrict__ w1p,
                            unsigned short* __restrict__ w2p,
                            float* __restrict__ b1p) {
    int idx = blockIdx.x * 256 + threadIdx.x;
    if (idx < 352 * 256) {                   // W1 folded + packed
        int k = idx >> 8, n = idx & 255;
        float a = gamma[n] * __builtin_amdgcn_rsqf(rvar[n] + 1e-5f);
        float v = 0.f;
        if (k < 288) {
            int g = k / 96, kk = k - g * 96;
            if (kk < 75) {
                int j = kk / 3, c = kk - j * 3;
                int base = (j * 12 + c) * HID_ + n;
                float wp = W1[base];
                float wv = W1[base + 3 * HID_];
                float wa = W1[base + 6 * HID_];
                float m  = jw[j] * a;
                v = (g == 0 ? (wp + wv + wa) : (g == 1 ? -(wv + 2.f * wa) : wa)) * m;
            }
        } else {
            int kk = k - 288;
            if (kk < 39) {
                int j = kk / 3, c = kk - j * 3;
                v = W1[(j * 12 + 9 + c) * HID_ + n] * jw[j] * a;
            }
        }
        int blk = (k >> 5) * 16 + (n >> 4);
        int off = blk * 512 + (((k >> 3) & 3) * 16 + (n & 15)) * 8 + (k & 7);
        w1p[off] = bf16_bits(v);
    } else if (idx < 352 * 256 + 256 * 128) {  // W2 packed
        int i2 = idx - 352 * 256;
        int k = i2 >> 7, n = i2 & 127;
        int blk = (k >> 5) * 8 + (n >> 4);
        int off = blk * 512 + (((k >> 3) & 3) * 16 + (n & 15)) * 8 + (k & 7);
        w2p[off] = bf16_bits(W2[k * OUT_ + n]);
    } else if (idx < 352 * 256 + 256 * 128 + 256) {   // folded bias
        int n = idx - (352 * 256 + 256 * 128);
        float a = gamma[n] * __builtin_amdgcn_rsqf(rvar[n] + 1e-5f);
        b1p[n] = fmaf(a, b1[n] - rmean[n], beta[n]);
    }
}

// --------------------------- main fused kernel ------------------------------
// LDS (single aliased region, 34304 B -> 4 blocks/CU):
//   phase 0/1 view: Ptile 66x100 ushort [0,13200) | ang 64x72 ushort
//                   [13216,22432) | pm[330] [22432,23752) | rs[66]f4 [23760,24816)
//   epilogue/2 view: hid 64x268 ushort [0,34304)
#define PT_STR   100
#define ANG_STR  72
#define HID_STR  268
#define LDS_ANG  13216
#define LDS_PM   22432
#define LDS_RS   23760
#define LDS_TOT  (64 * HID_STR * 2)          // 34304

__global__ __launch_bounds__(TPB, 8) void pose_mlp(
    const float* __restrict__ poses,
    const unsigned short* __restrict__ w1p,
    const unsigned short* __restrict__ w2p,
    const float* __restrict__ b1p,
    const float* __restrict__ b2,
    float* __restrict__ out)
{
    __shared__ __align__(16) unsigned char smem[LDS_TOT];
    const int tid  = threadIdx.x;
    const int lane = tid & 63;
    const int wv   = tid >> 6;               // 0..7
    const int t0   = blockIdx.x * MT_;
    const int s0   = t0 & (S_ - 1);

    unsigned short* pt  = (unsigned short*)smem;
    unsigned short* ang = (unsigned short*)(smem + LDS_ANG);
    float*  pm = (float*)(smem + LDS_PM);
    float4* rs = (float4*)(smem + LDS_RS);

    // early prefetch: phase-1 kc=0 B-frags (this wave's 2 n-tiles)
    short8 bw[2];
    #pragma unroll
    for (int ni = 0; ni < 2; ni++)
        bw[ni] = *(const short8*)(w1p + (unsigned)(wv * 2 + ni) * 512 + lane * 8);

    // ---- phase 0a: partial max-d2 per (frame, 5-joint group), no atomics ----
    for (int i = tid; i < 66 * 5; i += TPB) {
        int f = i / 5, grp = i - f * 5;
        int g = (s0 - 2 + f < 0) ? t0 : t0 - 2 + f;   // clamp at sequence start
        const float* P = poses + (size_t)g * 75;
        float r0 = P[0], r1 = P[1], r2 = P[2];
        float m2 = 0.f;
        #pragma unroll
        for (int jj = 0; jj < 5; jj++) {
            int j = grp * 5 + jj;
            float dx = P[j*3]   - r0;
            float dy = P[j*3+1] - r1;
            float dz = P[j*3+2] - r2;
            m2 = fmaxf(m2, fmaf(dx, dx, fmaf(dy, dy, dz * dz)));
        }
        pm[i] = m2;
    }
    __syncthreads();
    // ---- phase 0b: root + scale per frame ----
    if (tid < 66) {
        int g = (s0 - 2 + tid < 0) ? t0 : t0 - 2 + tid;
        const float* P = poses + (size_t)g * 75;
        const float* q = pm + tid * 5;
        float m2 = fmaxf(fmaxf(fmaxf(q[0], q[1]), fmaxf(q[2], q[3])), q[4]);
        float sc = __builtin_amdgcn_rcpf(__builtin_amdgcn_sqrtf(m2) + 1e-8f);
        rs[tid] = make_float4(P[0], P[1], P[2], sc);
    }
    __syncthreads();

    // ---- phase 0c: P-tile fill (centered·scaled), dword granularity ----
    // 66 rows x 50 dwords; cols 75..99 zero-padded
    for (int i = tid; i < 66 * 50; i += TPB) {
        int f = i / 50, p = i - f * 50;
        int r0 = 2 * p, r1 = r0 + 1;
        int g = (s0 - 2 + f < 0) ? t0 : t0 - 2 + f;
        const float* P = poses + (size_t)g * 75;
        float4 R = rs[f];
        float v0 = 0.f, v1 = 0.f;
        if (r0 < 75) {
            int c = r0 - (r0 / 3) * 3;
            float rt = (c == 0) ? R.x : ((c == 1) ? R.y : R.z);
            v0 = (P[r0] - rt) * R.w;
        }
        if (r1 < 75) {
            int c = r1 - (r1 / 3) * 3;
            float rt = (c == 0) ? R.x : ((c == 1) ? R.y : R.z);
            v1 = (P[r1] - rt) * R.w;
        }
        *(unsigned*)(pt + f * PT_STR + r0) = pkbf16(v0, v1);
    }

    // ---- phase 0d: angles per (token, edge); jw folded into Wang ----
    for (int i = tid; i < MT_ * 13; i += TPB) {
        int tt = i / 13, e = i - tt * 13;
        const float* P = poses + (size_t)(t0 + tt) * 75;
        int a0 = (int)((C0M >> (4 * e)) & 15) * 3;
        int a1 = (((int)((C1M >> (4 * e)) & 15)) + 1) * 3;
        float vx = P[a1] - P[a0], vy = P[a1+1] - P[a0+1], vz = P[a1+2] - P[a0+2];
        float d  = fmaf(vx, vx, fmaf(vy, vy, vz * vz));
        float inv = __builtin_amdgcn_rcpf(fmaxf(__builtin_amdgcn_sqrtf(d), 1e-12f));
        float A0 = facos(fminf(fmaxf(vx * inv, -1.f), 1.f));
        float A1 = facos(fminf(fmaxf(vy * inv, -1.f), 1.f));
        float A2 = facos(fminf(fmaxf(vz * inv, -1.f), 1.f));
        unsigned base = (unsigned)tt * ANG_STR + e * 3;
        ang[base]     = bf16_bits(A0);
        ang[base + 1] = bf16_bits(A1);
        ang[base + 2] = bf16_bits(A2);
    }
    // zero ang cols 39..63 (col 39 b16, cols 40..63 as 12 dwords)
    for (int i = tid; i < MT_ * 13; i += TPB) {
        int r = i / 13, q = i - r * 13;
        if (q == 0) ang[r * ANG_STR + 39] = 0;
        else *(unsigned*)(ang + r * ANG_STR + 40 + 2 * (q - 1)) = 0;
    }
    __syncthreads();

    // ---- phase 1: hidden = relu(A @ W1' + b1'), K=352, A from Ptile+ang ----
    floatx4 acc[4][2];
    #pragma unroll
    for (int mi = 0; mi < 4; mi++)
        #pragma unroll
        for (int ni = 0; ni < 2; ni++) acc[mi][ni] = (floatx4){0.f, 0.f, 0.f, 0.f};

    #pragma unroll 1
    for (int kc = 0; kc < NK1; kc++) {
        short8 bn[2];
        if (kc < NK1 - 1) {
            #pragma unroll
            for (int ni = 0; ni < 2; ni++)
                bn[ni] = *(const short8*)(w1p + (unsigned)((kc + 1) * 16 + wv * 2 + ni) * 512 + lane * 8);
        }
        short8 af[4];
        if (kc < 9) {                        // position groups: row = tt+2-grp
            int grp = kc / 3;
            int ko  = (kc - grp * 3) * 32 + (lane >> 4) * 8;
            #pragma unroll
            for (int mi = 0; mi < 4; mi++) {
                int row = mi * 16 + (lane & 15) + 2 - grp;
                af[mi] = *(const short8*)(pt + row * PT_STR + ko);
            }
        } else {                             // angle block
            int ko = (kc - 9) * 32 + (lane >> 4) * 8;
            #pragma unroll
            for (int mi = 0; mi < 4; mi++)
                af[mi] = *(const short8*)(ang + (mi * 16 + (lane & 15)) * ANG_STR + ko);
        }
        #pragma unroll
        for (int mi = 0; mi < 4; mi++)
            #pragma unroll
            for (int ni = 0; ni < 2; ni++)
                acc[mi][ni] = __builtin_amdgcn_mfma_f32_16x16x32_bf16(
                    af[mi], bw[ni], acc[mi][ni], 0, 0, 0);
        if (kc < NK1 - 1) {
            #pragma unroll
            for (int ni = 0; ni < 2; ni++) bw[ni] = bn[ni];
        }
    }

    // preload W2 kc=0 frag (independent of LDS)
    short8 bw2 = *(const short8*)(w2p + (unsigned)wv * 512 + lane * 8);

    __syncthreads();   // all waves done reading Ptile/ang -> safe to alias hid

    unsigned short* hid = (unsigned short*)smem;           // stride 268
    float bv[2];
    #pragma unroll
    for (int ni = 0; ni < 2; ni++) bv[ni] = b1p[wv * 32 + ni * 16 + (lane & 15)];
    #pragma unroll
    for (int mi = 0; mi < 4; mi++)
        #pragma unroll
        for (int ni = 0; ni < 2; ni++)
            #pragma unroll
            for (int r = 0; r < 4; r++) {
                float v = fmaxf(acc[mi][ni][r] + bv[ni], 0.f);
                int m   = mi * 16 + (lane >> 4) * 4 + r;   // C/D: row=(l>>4)*4+r
                int col = wv * 32 + ni * 16 + (lane & 15); //      col=l&15
                hid[m * HID_STR + col] = bf16_bits(v);
            }
    __syncthreads();   // hid visible

    // ---- phase 2: out = hidden @ W2 + b2; wave wv owns n-tile wv ----
    floatx4 acc2[4];
    #pragma unroll
    for (int mi = 0; mi < 4; mi++) acc2[mi] = (floatx4){0.f, 0.f, 0.f, 0.f};

    #pragma unroll 1
    for (int kc = 0; kc < 8; kc++) {
        short8 bn2;
        if (kc < 7)
            bn2 = *(const short8*)(w2p + (unsigned)((kc + 1) * 8 + wv) * 512 + lane * 8);
        short8 af[4];
        #pragma unroll
        for (int mi = 0; mi < 4; mi++)
            af[mi] = *(const short8*)(hid + (mi * 16 + (lane & 15)) * HID_STR + kc * 32 + (lane >> 4) * 8);
        #pragma unroll
        for (int mi = 0; mi < 4; mi++)
            acc2[mi] = __builtin_amdgcn_mfma_f32_16x16x32_bf16(
                af[mi], bw2, acc2[mi], 0, 0, 0);
        if (kc < 7) bw2 = bn2;
    }

    float c2 = b2[wv * 16 + (lane & 15)];
    #pragma unroll
    for (int mi = 0; mi < 4; mi++)
        #pragma unroll
        for (int r = 0; r < 4; r++) {
            int m   = mi * 16 + (lane >> 4) * 4 + r;
            int col = wv * 16 + (lane & 15);
            out[(size_t)(t0 + m) * OUT_ + col] = acc2[mi][r] + c2;
        }
}

// --------------------------- launch -----------------------------------------
extern "C" void kernel_launch(void* const* d_in, const int* in_sizes, int n_in,
                              void* d_out, int out_size, void* d_ws, size_t ws_size,
                              hipStream_t stream) {
    (void)in_sizes; (void)n_in; (void)out_size; (void)ws_size;
    const float* poses = (const float*)d_in[0];
    const float* W1    = (const float*)d_in[1];
    const float* b1    = (const float*)d_in[2];
    const float* gamma = (const float*)d_in[3];
    const float* beta  = (const float*)d_in[4];
    const float* rmean = (const float*)d_in[5];
    const float* rvar  = (const float*)d_in[6];
    const float* W2    = (const float*)d_in[7];
    const float* b2    = (const float*)d_in[8];
    const float* jw    = (const float*)d_in[9];

    unsigned short* w1p = (unsigned short*)d_ws;                 // 352*256 bf16
    unsigned short* w2p = w1p + 352 * HID_;                      // 256*128 bf16
    float* b1p = (float*)((char*)d_ws + (352 * HID_ + HID_ * OUT_) * 2);

    prep_kernel<<<481, 256, 0, stream>>>(W1, b1, gamma, beta, rmean, rvar, W2, jw,
                                         w1p, w2p, b1p);
    pose_mlp<<<2048, TPB, 0, stream>>>(poses, w1p, w2p, b1p, b2, (float*)d_out);
}